// Round 7
// baseline (204.601 us; speedup 1.0000x reference)
//
#include <hip/hip_runtime.h>
#include <hip/hip_bf16.h>

#define N_NODES 10000
#define KP      10240   // K padded; xwt pad region is ZERO
#define F       128
#define BK      64      // K-tile
#define NT      160     // KP / BK

typedef float  f32x4  __attribute__((ext_vector_type(4)));
typedef short  bf16x8 __attribute__((ext_vector_type(8)));
typedef short  s16x8  __attribute__((ext_vector_type(8)));
typedef short  s16x4  __attribute__((ext_vector_type(4)));

// f32 -> bf16 round-to-nearest-even (finite inputs only)
static __device__ __forceinline__ unsigned short f2bf(float f) {
    unsigned u = __builtin_bit_cast(unsigned, f);
    u += 0x7FFFu + ((u >> 16) & 1u);
    return (unsigned short)(u >> 16);
}

static __device__ __forceinline__ s16x4 pack4(f32x4 v) {
    s16x4 r;
    r[0] = (short)f2bf(v[0]); r[1] = (short)f2bf(v[1]);
    r[2] = (short)f2bf(v[2]); r[3] = (short)f2bf(v[3]);
    return r;
}

// ---------------------------------------------------------------------------
// Kernel 1: xwt = (X @ W1)^T bf16 in MFMA-native tiles:
//   [kc(320)][ct(8)][c(16)][k(32)] ; each 16c x 32k tile = 1KB contiguous.
// grid 640 x 256; pad k (nodes >= 10000) -> 0.
// ---------------------------------------------------------------------------
__global__ __launch_bounds__(256) void k_xw(const float* __restrict__ x,
                                            const float* __restrict__ W1,
                                            unsigned short* __restrict__ xwt) {
    __shared__ float xs[16][128];              // 8 KB
    __shared__ unsigned short ts[16][136];     // [node][col] staging (padded)
    const int t  = threadIdx.x;
    const int nb = blockIdx.x * 16;

    #pragma unroll
    for (int i = 0; i < 2; ++i) {
        int idx = t + i * 256;         // float4 index, 512 total
        int n   = idx >> 5;            // 32 float4 per row
        int c4  = idx & 31;
        int gn  = nb + n; if (gn > N_NODES - 1) gn = N_NODES - 1;
        f32x4 v = *reinterpret_cast<const f32x4*>(x + (size_t)gn * F + c4 * 4);
        *reinterpret_cast<f32x4*>(&xs[n][c4 * 4]) = v;
    }
    __syncthreads();

    const int f  = t & 127;
    const int ng = t >> 7;             // 0..1 -> nodes ng*8..+8
    float acc[8] = {0.f, 0.f, 0.f, 0.f, 0.f, 0.f, 0.f, 0.f};

    for (int c4 = 0; c4 < 32; ++c4) {
        float w0 = W1[(4 * c4 + 0) * F + f];
        float w1 = W1[(4 * c4 + 1) * F + f];
        float w2 = W1[(4 * c4 + 2) * F + f];
        float w3 = W1[(4 * c4 + 3) * F + f];
        #pragma unroll
        for (int i = 0; i < 8; ++i) {
            f32x4 xv = *reinterpret_cast<const f32x4*>(&xs[ng * 8 + i][c4 * 4]);
            acc[i] = fmaf(xv.x, w0, fmaf(xv.y, w1, fmaf(xv.z, w2, fmaf(xv.w, w3, acc[i]))));
        }
    }

    #pragma unroll
    for (int i = 0; i < 8; ++i) ts[ng * 8 + i][f] = f2bf(acc[i]);
    __syncthreads();

    {
        const int col = t >> 1, half = t & 1;
        s16x8 v8;
        #pragma unroll
        for (int i = 0; i < 8; ++i) {
            int n = half * 8 + i;
            v8[i] = (nb + n < N_NODES) ? (short)ts[n][col] : (short)0;
        }
        const int kc = nb >> 5, khalf = (nb >> 4) & 1;
        size_t off = (size_t)kc * 4096 + (size_t)(col >> 4) * 512
                   + (size_t)(col & 15) * 32 + khalf * 16 + half * 8;
        *reinterpret_cast<s16x8*>(xwt + off) = v8;
    }
}

// ---------------------------------------------------------------------------
// Kernel 2: out = relu(A @ XW + b1) @ W2 + b2, fused.
// grid 625 x 256; 16 rows/block; BK=64. Waves: ks = w>>1 (k-step), ch = w&1
// (col-half). B fragments load DIRECTLY from L2 (tiled xwt: each frag is a
// lane-contiguous 1KB wave-read) into named register sets, depth-2 prefetch.
// Only A goes through LDS (2KB double-buffered, nt loads). LDS traffic per
// block-tile: 6KB (was 38KB -> LDS-pipe bound at ~1015cy/tile, R5/R6).
// ---------------------------------------------------------------------------
#define SYNC() do { asm volatile("s_waitcnt lgkmcnt(0)" ::: "memory"); \
                    __builtin_amdgcn_s_barrier(); } while (0)

#define LOADA(tile, ra) do {                                                      \
    size_t _ao = arow + (size_t)(tile) * BK; if (_ao > alim) _ao = alim;          \
    ra = __builtin_nontemporal_load(reinterpret_cast<const f32x4*>(A + _ao));     \
} while (0)

#define LOADB(tile, b0, b1, b2, b3) do {                                          \
    const unsigned char* _p = xwt_b + (size_t)(2 * (tile) + ks) * 8192 + boB;     \
    b0 = *reinterpret_cast<const bf16x8*>(_p);                                    \
    b1 = *reinterpret_cast<const bf16x8*>(_p + 1024);                             \
    b2 = *reinterpret_cast<const bf16x8*>(_p + 2048);                             \
    b3 = *reinterpret_cast<const bf16x8*>(_p + 3072);                             \
} while (0)

#define WRTA(buf, ra) do {                                                        \
    *reinterpret_cast<s16x4*>((buf) + a_dst) = pack4(ra);                         \
} while (0)

#define COMP(buf, b0, b1, b2, b3) do {                                            \
    bf16x8 _af = *reinterpret_cast<const bf16x8*>((buf) + a_src);                 \
    acc0 = __builtin_amdgcn_mfma_f32_16x16x32_bf16(_af, b0, acc0, 0, 0, 0);       \
    acc1 = __builtin_amdgcn_mfma_f32_16x16x32_bf16(_af, b1, acc1, 0, 0, 0);       \
    acc2 = __builtin_amdgcn_mfma_f32_16x16x32_bf16(_af, b2, acc2, 0, 0, 0);       \
    acc3 = __builtin_amdgcn_mfma_f32_16x16x32_bf16(_af, b3, acc3, 0, 0, 0);       \
} while (0)

__global__ __launch_bounds__(256, 3) void k_gcn(const float* __restrict__ A,
                                                const unsigned short* __restrict__ xwt,
                                                const float* __restrict__ b1,
                                                const float* __restrict__ W2,
                                                const float* __restrict__ b2,
                                                float* __restrict__ out) {
    __shared__ __align__(16) unsigned char As0[2048];   // 16r x 64k bf16
    __shared__ __align__(16) unsigned char As1[2048];
    __shared__ float red[2][16][132];                   // ~17 KB ks-reduction

    const int t    = threadIdx.x;
    const int wave = t >> 6;
    const int lane = t & 63;
    const int l16  = lane & 15;
    const int g    = lane >> 4;
    const int ks   = wave >> 1;      // k-step (0..1) within tile
    const int ch   = wave & 1;       // col-half
    const int rbase = blockIdx.x * 16;   // 10000 = 625*16

    const unsigned char* const xwt_b = reinterpret_cast<const unsigned char*>(xwt);

    // A staging: thread t -> row t>>4, 4-float chunk q = t&15
    const int sr = t >> 4, q = t & 15;
    const size_t arow = (size_t)(rbase + sr) * N_NODES + q * 4;
    const size_t alim = (size_t)N_NODES * N_NODES - 4;
    // bf16 LDS [16 rows][8 x 16B units], unit swizzled ^ (row&7)
    const int a_dst = sr * 128 + ((q >> 1) ^ (sr & 7)) * 16 + (q & 1) * 8;
    const int a_src = l16 * 128 + ((ks * 4 + g) ^ (l16 & 7)) * 16;

    // B frag byte offset within a kc-slab: col-tile (ch*4+f), lane part
    const int boB = ch * 4096 + l16 * 64 + g * 16;

    f32x4 acc0 = {0.f, 0.f, 0.f, 0.f}, acc1 = acc0, acc2 = acc0, acc3 = acc0;

    f32x4 raA, raB;
    bf16x8 bA0, bA1, bA2, bA3, bB0, bB1, bB2, bB3;

    // prologue: 2 tiles in flight
    LOADA(0, raA); LOADB(0, bA0, bA1, bA2, bA3);
    LOADA(1, raB); LOADB(1, bB0, bB1, bB2, bB3);
    WRTA(As0, raA);
    SYNC();

    for (int tile = 0; tile < NT; tile += 2) {
        // even: compute tile (As0, setA); refill setA with tile+2
        COMP(As0, bA0, bA1, bA2, bA3);
        if (tile + 2 < NT) { LOADA(tile + 2, raA); LOADB(tile + 2, bA0, bA1, bA2, bA3); }
        WRTA(As1, raB);
        SYNC();
        // odd: compute tile+1 (As1, setB); refill setB with tile+3
        COMP(As1, bB0, bB1, bB2, bB3);
        if (tile + 3 < NT) { LOADA(tile + 3, raB); LOADB(tile + 3, bB0, bB1, bB2, bB3); }
        if (tile + 2 < NT) WRTA(As0, raA);
        SYNC();
    }

    // epilogue: reduce over ks pairs + bias + relu + dot(W2) + b2
    // C/D layout (m89): col = lane&15, row = (lane>>4)*4 + reg
    #pragma unroll
    for (int e = 0; e < 4; ++e) {
        red[ks][g * 4 + e][ch * 64 +  0 + l16] = acc0[e];
        red[ks][g * 4 + e][ch * 64 + 16 + l16] = acc1[e];
        red[ks][g * 4 + e][ch * 64 + 32 + l16] = acc2[e];
        red[ks][g * 4 + e][ch * 64 + 48 + l16] = acc3[e];
    }
    __syncthreads();

    {
        const int r  = t >> 4;          // 0..15 local row
        const int jj = t & 15;          // 16 threads/row, 8 cols each
        float p = 0.f;
        #pragma unroll
        for (int i = 0; i < 8; ++i) {
            int c = jj * 8 + i;
            float v = red[0][r][c] + red[1][r][c] + b1[c];
            v = fmaxf(v, 0.f);
            p = fmaf(v, W2[c], p);
        }
        p += __shfl_xor(p, 1);
        p += __shfl_xor(p, 2);
        p += __shfl_xor(p, 4);
        p += __shfl_xor(p, 8);
        if (jj == 0) out[rbase + r] = p + b2[0];
    }
}

extern "C" void kernel_launch(void* const* d_in, const int* in_sizes, int n_in,
                              void* d_out, int out_size, void* d_ws, size_t ws_size,
                              hipStream_t stream) {
    const float* x  = (const float*)d_in[0];
    const float* a  = (const float*)d_in[1];
    const float* W1 = (const float*)d_in[2];
    const float* b1 = (const float*)d_in[3];
    const float* W2 = (const float*)d_in[4];
    const float* b2 = (const float*)d_in[5];
    float* out = (float*)d_out;
    unsigned short* xwt = (unsigned short*)d_ws;   // 320*8KB = 2.62 MB tiled scratch

    k_xw<<<640, 256, 0, stream>>>(x, W1, xwt);     // fills all slabs incl. zero pad
    k_gcn<<<625, 256, 0, stream>>>(a, xwt, b1, W2, b2, out);
}

// Round 8
// 160.830 us; speedup vs baseline: 1.2722x; 1.2722x over previous
//
#include <hip/hip_runtime.h>
#include <hip/hip_bf16.h>

#define N_NODES 10000
#define KP      10240   // K padded; xwt pad slabs are ZERO
#define F       128
#define SPLITS  8
#define KSPLIT  1280    // KP / SPLITS
#define BK      64
#define TPS     20      // tiles per split
#define BM      64
#define MBLK    157     // ceil(10000/64)
#define PROWS   10048   // MBLK*64

typedef float  f32x4  __attribute__((ext_vector_type(4)));
typedef short  bf16x8 __attribute__((ext_vector_type(8)));
typedef short  s16x8  __attribute__((ext_vector_type(8)));

static __device__ __forceinline__ unsigned short f2bf(float f) {
    unsigned u = __builtin_bit_cast(unsigned, f);
    u += 0x7FFFu + ((u >> 16) & 1u);
    return (unsigned short)(u >> 16);
}

static __device__ __forceinline__ bf16x8 pack8(f32x4 lo, f32x4 hi) {
    bf16x8 r;
    r[0] = (short)f2bf(lo[0]); r[1] = (short)f2bf(lo[1]);
    r[2] = (short)f2bf(lo[2]); r[3] = (short)f2bf(lo[3]);
    r[4] = (short)f2bf(hi[0]); r[5] = (short)f2bf(hi[1]);
    r[6] = (short)f2bf(hi[2]); r[7] = (short)f2bf(hi[3]);
    return r;
}

// ---------------------------------------------------------------------------
// Kernel 1: xwt = (X @ W1)^T bf16, tiled+swizzled for direct global_load_lds:
//   16B unit u = kc2*512 + ct*64 + c*4 + ku within each 16KB slab-pair,
//   STORED at position p = u ^ (c&7)  (c = col%16, ku = k8-chunk 0..3).
// grid 640 x 256; pad k (nodes >= 10000) -> 0.
// ---------------------------------------------------------------------------
__global__ __launch_bounds__(256) void k_xw(const float* __restrict__ x,
                                            const float* __restrict__ W1,
                                            unsigned short* __restrict__ xwt) {
    __shared__ float xs[16][128];
    __shared__ unsigned short ts[16][136];
    const int t  = threadIdx.x;
    const int nb = blockIdx.x * 16;

    #pragma unroll
    for (int i = 0; i < 2; ++i) {
        int idx = t + i * 256;
        int n   = idx >> 5;
        int c4  = idx & 31;
        int gn  = nb + n; if (gn > N_NODES - 1) gn = N_NODES - 1;
        f32x4 v = *reinterpret_cast<const f32x4*>(x + (size_t)gn * F + c4 * 4);
        *reinterpret_cast<f32x4*>(&xs[n][c4 * 4]) = v;
    }
    __syncthreads();

    const int f  = t & 127;
    const int ng = t >> 7;
    float acc[8] = {0.f, 0.f, 0.f, 0.f, 0.f, 0.f, 0.f, 0.f};

    for (int c4 = 0; c4 < 32; ++c4) {
        float w0 = W1[(4 * c4 + 0) * F + f];
        float w1 = W1[(4 * c4 + 1) * F + f];
        float w2 = W1[(4 * c4 + 2) * F + f];
        float w3 = W1[(4 * c4 + 3) * F + f];
        #pragma unroll
        for (int i = 0; i < 8; ++i) {
            f32x4 xv = *reinterpret_cast<const f32x4*>(&xs[ng * 8 + i][c4 * 4]);
            acc[i] = fmaf(xv.x, w0, fmaf(xv.y, w1, fmaf(xv.z, w2, fmaf(xv.w, w3, acc[i]))));
        }
    }

    #pragma unroll
    for (int i = 0; i < 8; ++i) ts[ng * 8 + i][f] = f2bf(acc[i]);
    __syncthreads();

    {
        const int col = t >> 1, half = t & 1;
        s16x8 v8;
        #pragma unroll
        for (int i = 0; i < 8; ++i) {
            int n = half * 8 + i;
            v8[i] = (nb + n < N_NODES) ? (short)ts[n][col] : (short)0;
        }
        const int c  = col & 15, ct = col >> 4;
        const int kc = nb >> 5, khalf = (nb >> 4) & 1;
        const int ku = khalf * 2 + half;
        int upair = (kc & 1) * 512 + ct * 64 + c * 4 + ku;
        size_t off = (size_t)(kc >> 1) * 8192 + (size_t)(upair ^ (c & 7)) * 8;
        *reinterpret_cast<s16x8*>(xwt + off) = v8;
    }
}

// ---------------------------------------------------------------------------
// Kernel 2: partial GEMM, split-K. grid (157 mblocks x 8 splits) x 512 thr.
// Block: 64 rows x 128 cols x 1280 k. Wave (mq=w>>2, cq=w&3): 32x32 subtile.
// B: global_load_lds from tiled/swizzled xwt (16KB/tile). A: reg-staged
// f32->bf16 into XOR-swizzled LDS (8KB/tile). Double-buffered, m97 2-barrier.
// ---------------------------------------------------------------------------
#define GLOAD(gsrc, ldst) __builtin_amdgcn_global_load_lds(                      \
    (const __attribute__((address_space(1))) unsigned int*)(gsrc),               \
    (__attribute__((address_space(3))) unsigned int*)(ldst), 16, 0, 0)

#define MFMA(a, b, c) __builtin_amdgcn_mfma_f32_16x16x32_bf16(a, b, c, 0, 0, 0)

__global__ __launch_bounds__(512) void k_gcn(const float* __restrict__ A,
                                             const unsigned short* __restrict__ xwt,
                                             float* __restrict__ P) {
    __shared__ __align__(16) unsigned char Bs[2][16384];
    __shared__ __align__(16) unsigned char As[2][8192];

    const int t    = threadIdx.x;
    const int w    = t >> 6;
    const int lane = t & 63;
    const int l16  = lane & 15;
    const int g    = lane >> 4;
    const int mq   = w >> 2;         // 0..1 : 32-row half
    const int cq   = w & 3;          // 0..3 : 32-col quarter
    const int mb    = blockIdx.x % MBLK;
    const int split = blockIdx.x / MBLK;
    const int rbase = mb * BM;
    const int k0    = split * KSPLIT;

    // ---- A staging: thread t loads 8 floats of row (t>>3), chunk (t&7) ----
    const int sr = t >> 3, tc = t & 7;
    int arow = rbase + sr; if (arow > N_NODES - 1) arow = N_NODES - 1;
    const float* aptr = A + (size_t)arow * N_NODES + k0 + tc * 8;
    const size_t alim = (size_t)N_NODES * N_NODES - 8;   // clamp (reads 8 floats)
    const size_t abase0 = (size_t)arow * N_NODES + k0 + tc * 8;
    const int a_w = (sr * 8 + (tc ^ (sr & 7))) * 16;     // LDS byte offset

    const unsigned char* const xb = reinterpret_cast<const unsigned char*>(xwt);

    // ---- fragment read byte offsets ----
    // A: row r = mq*32 + mf*16 + l16, unit ku = kf*4+g, addr = r*128 + (ku^(r&7))*16
    int ar00, ar01, ar10, ar11;
    {
        int r0 = mq * 32 + l16, r1 = mq * 32 + 16 + l16;
        ar00 = r0 * 128 + ((0 * 4 + g) ^ (r0 & 7)) * 16;
        ar01 = r0 * 128 + ((1 * 4 + g) ^ (r0 & 7)) * 16;
        ar10 = r1 * 128 + ((0 * 4 + g) ^ (r1 & 7)) * 16;
        ar11 = r1 * 128 + ((1 * 4 + g) ^ (r1 & 7)) * 16;
    }
    // B: unit u = kf*512 + (cq*2+cf)*64 + l16*4 + g, addr = (u ^ (l16&7))*16
    int br00, br01, br10, br11;
    {
        int m = l16 & 7;
        br00 = ((0 * 512 + (cq * 2 + 0) * 64 + l16 * 4 + g) ^ m) * 16;
        br01 = ((1 * 512 + (cq * 2 + 0) * 64 + l16 * 4 + g) ^ m) * 16;
        br10 = ((0 * 512 + (cq * 2 + 1) * 64 + l16 * 4 + g) ^ m) * 16;
        br11 = ((1 * 512 + (cq * 2 + 1) * 64 + l16 * 4 + g) ^ m) * 16;
    }

    f32x4 acc00 = {0.f, 0.f, 0.f, 0.f}, acc01 = acc00, acc10 = acc00, acc11 = acc00;

    // ---- staging macro: issue A reg-loads, B global_load_lds, pack+write A ----
#define STAGE(tile, buf) do {                                                    \
    size_t _ao = abase0 + (size_t)(tile) * BK;                                   \
    if (_ao > alim) _ao = alim;                                                  \
    f32x4 _a0 = __builtin_nontemporal_load(reinterpret_cast<const f32x4*>(A + _ao));      \
    f32x4 _a1 = __builtin_nontemporal_load(reinterpret_cast<const f32x4*>(A + _ao) + 1);  \
    const unsigned char* _cb = xb + (size_t)(split * 40 + 2 * (tile)) * 8192;    \
    GLOAD(_cb + (w * 2 + 0) * 1024 + lane * 16, &Bs[buf][(w * 2 + 0) * 1024]);   \
    GLOAD(_cb + (w * 2 + 1) * 1024 + lane * 16, &Bs[buf][(w * 2 + 1) * 1024]);   \
    *reinterpret_cast<bf16x8*>(&As[buf][a_w]) = pack8(_a0, _a1);                 \
} while (0)

#define COMPUTE(buf) do {                                                        \
    bf16x8 af00 = *reinterpret_cast<const bf16x8*>(&As[buf][ar00]);              \
    bf16x8 af01 = *reinterpret_cast<const bf16x8*>(&As[buf][ar01]);              \
    bf16x8 af10 = *reinterpret_cast<const bf16x8*>(&As[buf][ar10]);              \
    bf16x8 af11 = *reinterpret_cast<const bf16x8*>(&As[buf][ar11]);              \
    bf16x8 bf00 = *reinterpret_cast<const bf16x8*>(&Bs[buf][br00]);              \
    bf16x8 bf01 = *reinterpret_cast<const bf16x8*>(&Bs[buf][br01]);              \
    bf16x8 bf10 = *reinterpret_cast<const bf16x8*>(&Bs[buf][br10]);              \
    bf16x8 bf11 = *reinterpret_cast<const bf16x8*>(&Bs[buf][br11]);              \
    acc00 = MFMA(af00, bf00, acc00); acc00 = MFMA(af01, bf01, acc00);            \
    acc01 = MFMA(af00, bf10, acc01); acc01 = MFMA(af01, bf11, acc01);            \
    acc10 = MFMA(af10, bf00, acc10); acc10 = MFMA(af11, bf01, acc10);            \
    acc11 = MFMA(af10, bf10, acc11); acc11 = MFMA(af11, bf11, acc11);            \
} while (0)

    STAGE(0, 0);
    __syncthreads();
    for (int tile = 0; tile < TPS; ++tile) {
        if (tile + 1 < TPS) STAGE(tile + 1, (tile + 1) & 1);
        COMPUTE(tile & 1);
        __syncthreads();
    }

    // ---- write f32 partials: row = rbase+mq*32+mf*16+g*4+e, col = cq*32+cf*16+l16
    {
        float* Pp = P + ((size_t)split * PROWS + rbase) * F;
        #pragma unroll
        for (int e = 0; e < 4; ++e) {
            Pp[(size_t)(mq * 32 +  0 + g * 4 + e) * F + cq * 32 +  0 + l16] = acc00[e];
            Pp[(size_t)(mq * 32 +  0 + g * 4 + e) * F + cq * 32 + 16 + l16] = acc01[e];
            Pp[(size_t)(mq * 32 + 16 + g * 4 + e) * F + cq * 32 +  0 + l16] = acc10[e];
            Pp[(size_t)(mq * 32 + 16 + g * 4 + e) * F + cq * 32 + 16 + l16] = acc11[e];
        }
    }
#undef STAGE
#undef COMPUTE
}

// ---------------------------------------------------------------------------
// Kernel 3: out[r] = relu(sum_s P[s][r][:] + b1) . W2 + b2. grid 5000 x 256.
// ---------------------------------------------------------------------------
__global__ __launch_bounds__(256) void k_red(const float* __restrict__ P,
                                             const float* __restrict__ b1,
                                             const float* __restrict__ W2,
                                             const float* __restrict__ b2,
                                             float* __restrict__ out) {
    __shared__ float sred[4];
    const int t   = threadIdx.x;
    const int row = blockIdx.x * 2 + (t >> 7);
    const int c   = t & 127;

    float v = 0.f;
    #pragma unroll
    for (int s = 0; s < SPLITS; ++s)
        v += P[((size_t)s * PROWS + row) * F + c];
    v = fmaxf(v + b1[c], 0.f) * W2[c];

    v += __shfl_xor(v, 1);
    v += __shfl_xor(v, 2);
    v += __shfl_xor(v, 4);
    v += __shfl_xor(v, 8);
    v += __shfl_xor(v, 16);
    v += __shfl_xor(v, 32);
    if ((t & 63) == 0) sred[t >> 6] = v;
    __syncthreads();
    if (t < 2) out[blockIdx.x * 2 + t] = sred[t * 2] + sred[t * 2 + 1] + b2[0];
}

extern "C" void kernel_launch(void* const* d_in, const int* in_sizes, int n_in,
                              void* d_out, int out_size, void* d_ws, size_t ws_size,
                              hipStream_t stream) {
    const float* x  = (const float*)d_in[0];
    const float* a  = (const float*)d_in[1];
    const float* W1 = (const float*)d_in[2];
    const float* b1 = (const float*)d_in[3];
    const float* W2 = (const float*)d_in[4];
    const float* b2 = (const float*)d_in[5];
    float* out = (float*)d_out;

    unsigned short* xwt = (unsigned short*)d_ws;                  // 2.62 MB tiled
    float* P = (float*)((char*)d_ws + (size_t)(32 << 20));        // 8x10048x128 f32

    k_xw<<<640, 256, 0, stream>>>(x, W1, xwt);
    k_gcn<<<MBLK * SPLITS, 512, 0, stream>>>(a, xwt, P);
    k_red<<<5000, 256, 0, stream>>>(P, b1, W2, b2, out);
}

// Round 9
// 140.666 us; speedup vs baseline: 1.4545x; 1.1434x over previous
//
#include <hip/hip_runtime.h>
#include <hip/hip_bf16.h>

#define N_NODES 10000
#define KP      10240   // K padded; xwt pad slabs are ZERO
#define F       128
#define SPLITS  8
#define KSPLIT  1280    // KP / SPLITS
#define BK      64
#define TPS     20      // tiles per split
#define BM      64
#define MBLK    157     // ceil(10000/64)
#define PROWS   10048   // MBLK*64

typedef float  f32x4  __attribute__((ext_vector_type(4)));
typedef short  bf16x8 __attribute__((ext_vector_type(8)));
typedef short  s16x8  __attribute__((ext_vector_type(8)));

static __device__ __forceinline__ unsigned short f2bf(float f) {
    unsigned u = __builtin_bit_cast(unsigned, f);
    u += 0x7FFFu + ((u >> 16) & 1u);
    return (unsigned short)(u >> 16);
}

static __device__ __forceinline__ bf16x8 pack8(f32x4 lo, f32x4 hi) {
    bf16x8 r;
    r[0] = (short)f2bf(lo[0]); r[1] = (short)f2bf(lo[1]);
    r[2] = (short)f2bf(lo[2]); r[3] = (short)f2bf(lo[3]);
    r[4] = (short)f2bf(hi[0]); r[5] = (short)f2bf(hi[1]);
    r[6] = (short)f2bf(hi[2]); r[7] = (short)f2bf(hi[3]);
    return r;
}

// ---------------------------------------------------------------------------
// Kernel 1: xwt = (X @ W1)^T bf16, tiled+swizzled for direct global_load_lds:
//   16B unit u = kc2*512 + ct*64 + c*4 + ku within each 16KB slab-pair,
//   STORED at position p = u ^ (c&7)  (c = col%16, ku = k8-chunk 0..3).
// grid 640 x 256; pad k (nodes >= 10000) -> 0.
// ---------------------------------------------------------------------------
__global__ __launch_bounds__(256) void k_xw(const float* __restrict__ x,
                                            const float* __restrict__ W1,
                                            unsigned short* __restrict__ xwt) {
    __shared__ float xs[16][128];
    __shared__ unsigned short ts[16][136];
    const int t  = threadIdx.x;
    const int nb = blockIdx.x * 16;

    #pragma unroll
    for (int i = 0; i < 2; ++i) {
        int idx = t + i * 256;
        int n   = idx >> 5;
        int c4  = idx & 31;
        int gn  = nb + n; if (gn > N_NODES - 1) gn = N_NODES - 1;
        f32x4 v = *reinterpret_cast<const f32x4*>(x + (size_t)gn * F + c4 * 4);
        *reinterpret_cast<f32x4*>(&xs[n][c4 * 4]) = v;
    }
    __syncthreads();

    const int f  = t & 127;
    const int ng = t >> 7;
    float acc[8] = {0.f, 0.f, 0.f, 0.f, 0.f, 0.f, 0.f, 0.f};

    for (int c4 = 0; c4 < 32; ++c4) {
        float w0 = W1[(4 * c4 + 0) * F + f];
        float w1 = W1[(4 * c4 + 1) * F + f];
        float w2 = W1[(4 * c4 + 2) * F + f];
        float w3 = W1[(4 * c4 + 3) * F + f];
        #pragma unroll
        for (int i = 0; i < 8; ++i) {
            f32x4 xv = *reinterpret_cast<const f32x4*>(&xs[ng * 8 + i][c4 * 4]);
            acc[i] = fmaf(xv.x, w0, fmaf(xv.y, w1, fmaf(xv.z, w2, fmaf(xv.w, w3, acc[i]))));
        }
    }

    #pragma unroll
    for (int i = 0; i < 8; ++i) ts[ng * 8 + i][f] = f2bf(acc[i]);
    __syncthreads();

    {
        const int col = t >> 1, half = t & 1;
        s16x8 v8;
        #pragma unroll
        for (int i = 0; i < 8; ++i) {
            int n = half * 8 + i;
            v8[i] = (nb + n < N_NODES) ? (short)ts[n][col] : (short)0;
        }
        const int c  = col & 15, ct = col >> 4;
        const int kc = nb >> 5, khalf = (nb >> 4) & 1;
        const int ku = khalf * 2 + half;
        int upair = (kc & 1) * 512 + ct * 64 + c * 4 + ku;
        size_t off = (size_t)(kc >> 1) * 8192 + (size_t)(upair ^ (c & 7)) * 8;
        *reinterpret_cast<s16x8*>(xwt + off) = v8;
    }
}

// ---------------------------------------------------------------------------
// Kernel 2: partial GEMM, split-K. grid (157 mblocks x 8 splits) x 512 thr.
// Block: 64 rows x 128 cols x 1280 k. Wave (mq=w>>2, cq=w&3): 32x32 subtile.
// A: 512B-per-row visits (DRAM-activate relief), pair-loaded every other tile
//    into a 6-slot rotating LDS ring (reg-staged f32->bf16, XOR-swizzled).
// B: global_load_lds from tiled/swizzled xwt (16KB/tile), double-buffered.
// ---------------------------------------------------------------------------
#define GLOAD(gsrc, ldst) __builtin_amdgcn_global_load_lds(                      \
    (const __attribute__((address_space(1))) unsigned int*)(gsrc),               \
    (__attribute__((address_space(3))) unsigned int*)(ldst), 16, 0, 0)

#define MFMA(a, b, c) __builtin_amdgcn_mfma_f32_16x16x32_bf16(a, b, c, 0, 0, 0)

__global__ __launch_bounds__(512) void k_gcn(const float* __restrict__ A,
                                             const unsigned short* __restrict__ xwt,
                                             float* __restrict__ P) {
    __shared__ __align__(16) unsigned char Bs[2][16384];   // 32 KB
    __shared__ __align__(16) unsigned char As[6][8192];    // 48 KB (6-slot ring)

    const int t    = threadIdx.x;
    const int w    = t >> 6;
    const int lane = t & 63;
    const int l16  = lane & 15;
    const int g    = lane >> 4;
    const int mq   = w >> 2;         // 0..1 : 32-row half
    const int cq   = w & 3;          // 0..3 : 32-col quarter
    const int mb    = blockIdx.x % MBLK;
    const int split = blockIdx.x / MBLK;
    const int rbase = mb * BM;
    const int k0    = split * KSPLIT;

    // ---- A staging: thread t -> row (t>>3), 64B chunk (t&7) of a 512B pair ----
    const int sr = t >> 3, c8 = t & 7;
    int arow = rbase + sr; if (arow > N_NODES - 1) arow = N_NODES - 1;
    const size_t abase0 = (size_t)arow * N_NODES + k0 + c8 * 16;
    const size_t alim   = (size_t)N_NODES * N_NODES - 16;   // reads 16 floats

    const unsigned char* const xb = reinterpret_cast<const unsigned char*>(xwt);
    unsigned char* const Asb = &As[0][0];

    // ---- fragment read byte offsets (within one A slot / one B buffer) ----
    int ar00, ar01, ar10, ar11;
    {
        int r0 = mq * 32 + l16, r1 = mq * 32 + 16 + l16;
        ar00 = r0 * 128 + ((0 * 4 + g) ^ (r0 & 7)) * 16;
        ar01 = r0 * 128 + ((1 * 4 + g) ^ (r0 & 7)) * 16;
        ar10 = r1 * 128 + ((0 * 4 + g) ^ (r1 & 7)) * 16;
        ar11 = r1 * 128 + ((1 * 4 + g) ^ (r1 & 7)) * 16;
    }
    int br00, br01, br10, br11;
    {
        int m = l16 & 7;
        br00 = ((0 * 512 + (cq * 2 + 0) * 64 + l16 * 4 + g) ^ m) * 16;
        br01 = ((1 * 512 + (cq * 2 + 0) * 64 + l16 * 4 + g) ^ m) * 16;
        br10 = ((0 * 512 + (cq * 2 + 1) * 64 + l16 * 4 + g) ^ m) * 16;
        br11 = ((1 * 512 + (cq * 2 + 1) * 64 + l16 * 4 + g) ^ m) * 16;
    }

    f32x4 acc00 = {0.f, 0.f, 0.f, 0.f}, acc01 = acc00, acc10 = acc00, acc11 = acc00;
    f32x4 la0, la1, la2, la3;   // A pair-stage regs (64B)

    // load 512B-per-row pair covering sub-tiles {tp, tp+1}
#define LOADA(tp) do {                                                           \
    size_t _ao = abase0 + (size_t)(tp) * BK;                                     \
    if (_ao > alim) _ao = alim;                                                  \
    const f32x4* _p = reinterpret_cast<const f32x4*>(A + _ao);                   \
    la0 = _p[0]; la1 = _p[1]; la2 = _p[2]; la3 = _p[3];                          \
} while (0)

    // write staged pair into ring slots s0 (k-half 0) / s1 (k-half 1)
#define WRITEA(s0, s1) do {                                                      \
    bf16x8 _w0 = pack8(la0, la1);                                                \
    bf16x8 _w1 = pack8(la2, la3);                                                \
    int _slot = (c8 < 4) ? (s0) : (s1);                                          \
    int _u0   = (c8 & 3) * 2;                                                    \
    unsigned char* _pp = Asb + _slot * 8192 + sr * 128;                          \
    *reinterpret_cast<bf16x8*>(_pp + ((_u0    ) ^ (sr & 7)) * 16) = _w0;         \
    *reinterpret_cast<bf16x8*>(_pp + ((_u0 + 1) ^ (sr & 7)) * 16) = _w1;         \
} while (0)

#define STAGEB(tile, buf) do {                                                   \
    const unsigned char* _cb = xb + (size_t)(split * 40 + 2 * (tile)) * 8192;    \
    GLOAD(_cb + (w * 2 + 0) * 1024 + lane * 16, &Bs[buf][(w * 2 + 0) * 1024]);   \
    GLOAD(_cb + (w * 2 + 1) * 1024 + lane * 16, &Bs[buf][(w * 2 + 1) * 1024]);   \
} while (0)

#define COMPUTE(slot, buf) do {                                                  \
    const unsigned char* _as = Asb + (slot) * 8192;                              \
    bf16x8 af00 = *reinterpret_cast<const bf16x8*>(_as + ar00);                  \
    bf16x8 af01 = *reinterpret_cast<const bf16x8*>(_as + ar01);                  \
    bf16x8 af10 = *reinterpret_cast<const bf16x8*>(_as + ar10);                  \
    bf16x8 af11 = *reinterpret_cast<const bf16x8*>(_as + ar11);                  \
    bf16x8 bf00 = *reinterpret_cast<const bf16x8*>(&Bs[buf][br00]);              \
    bf16x8 bf01 = *reinterpret_cast<const bf16x8*>(&Bs[buf][br01]);              \
    bf16x8 bf10 = *reinterpret_cast<const bf16x8*>(&Bs[buf][br10]);              \
    bf16x8 bf11 = *reinterpret_cast<const bf16x8*>(&Bs[buf][br11]);              \
    acc00 = MFMA(af00, bf00, acc00); acc00 = MFMA(af01, bf01, acc00);            \
    acc01 = MFMA(af00, bf10, acc01); acc01 = MFMA(af01, bf11, acc01);            \
    acc10 = MFMA(af10, bf00, acc10); acc10 = MFMA(af11, bf01, acc10);            \
    acc11 = MFMA(af10, bf10, acc11); acc11 = MFMA(af11, bf11, acc11);            \
} while (0)

    // prologue: A tiles 0..3 into slots 0..3; B tile 0
    LOADA(0); WRITEA(0, 1);
    LOADA(2); WRITEA(2, 3);
    STAGEB(0, 0);
    __syncthreads();

    for (int tile = 0; tile < TPS; ++tile) {
        if (tile + 1 < TPS) STAGEB(tile + 1, (tile + 1) & 1);
        const bool pf = ((tile & 1) == 0) && (tile + 4 < TPS);
        if (pf) LOADA(tile + 4);
        COMPUTE(tile % 6, tile & 1);
        if (pf) WRITEA((tile + 4) % 6, (tile + 5) % 6);
        __syncthreads();
    }

    // ---- write f32 partials: row = rbase+mq*32+..., col = cq*32+... ----
    {
        float* Pp = P + ((size_t)split * PROWS + rbase) * F;
        #pragma unroll
        for (int e = 0; e < 4; ++e) {
            Pp[(size_t)(mq * 32 +  0 + g * 4 + e) * F + cq * 32 +  0 + l16] = acc00[e];
            Pp[(size_t)(mq * 32 +  0 + g * 4 + e) * F + cq * 32 + 16 + l16] = acc01[e];
            Pp[(size_t)(mq * 32 + 16 + g * 4 + e) * F + cq * 32 +  0 + l16] = acc10[e];
            Pp[(size_t)(mq * 32 + 16 + g * 4 + e) * F + cq * 32 + 16 + l16] = acc11[e];
        }
    }
#undef LOADA
#undef WRITEA
#undef STAGEB
#undef COMPUTE
}

// ---------------------------------------------------------------------------
// Kernel 3: out[r] = relu(sum_s P[s][r][:] + b1) . W2 + b2. grid 5000 x 256.
// ---------------------------------------------------------------------------
__global__ __launch_bounds__(256) void k_red(const float* __restrict__ P,
                                             const float* __restrict__ b1,
                                             const float* __restrict__ W2,
                                             const float* __restrict__ b2,
                                             float* __restrict__ out) {
    __shared__ float sred[4];
    const int t   = threadIdx.x;
    const int row = blockIdx.x * 2 + (t >> 7);
    const int c   = t & 127;

    float v = 0.f;
    #pragma unroll
    for (int s = 0; s < SPLITS; ++s)
        v += P[((size_t)s * PROWS + row) * F + c];
    v = fmaxf(v + b1[c], 0.f) * W2[c];

    v += __shfl_xor(v, 1);
    v += __shfl_xor(v, 2);
    v += __shfl_xor(v, 4);
    v += __shfl_xor(v, 8);
    v += __shfl_xor(v, 16);
    v += __shfl_xor(v, 32);
    if ((t & 63) == 0) sred[t >> 6] = v;
    __syncthreads();
    if (t < 2) out[blockIdx.x * 2 + t] = sred[t * 2] + sred[t * 2 + 1] + b2[0];
}

extern "C" void kernel_launch(void* const* d_in, const int* in_sizes, int n_in,
                              void* d_out, int out_size, void* d_ws, size_t ws_size,
                              hipStream_t stream) {
    const float* x  = (const float*)d_in[0];
    const float* a  = (const float*)d_in[1];
    const float* W1 = (const float*)d_in[2];
    const float* b1 = (const float*)d_in[3];
    const float* W2 = (const float*)d_in[4];
    const float* b2 = (const float*)d_in[5];
    float* out = (float*)d_out;

    unsigned short* xwt = (unsigned short*)d_ws;                  // 2.62 MB tiled
    float* P = (float*)((char*)d_ws + (size_t)(32 << 20));        // 8x10048x128 f32

    k_xw<<<640, 256, 0, stream>>>(x, W1, xwt);
    k_gcn<<<MBLK * SPLITS, 512, 0, stream>>>(a, xwt, P);
    k_red<<<5000, 256, 0, stream>>>(P, b1, W2, b2, out);
}